// Round 1
// baseline (99.505 us; speedup 1.0000x reference)
//
#include <hip/hip_runtime.h>

// Problem: B=16, S=2048, D=64, fp32.
// out[b] = V[b] @ (K[b]^T @ Q[b])   -- avoids the SxS intermediate.

#define BATCH 16
#define SEQ   2048
#define DIM   64
#define SCHUNK 128          // seq rows per block in kernel A
#define NCHUNK (SEQ / SCHUNK)
#define RBLK  64            // V rows per block in kernel B
#define VPAD  68            // padded LDS row stride (floats): 68%32=4 -> 2-way max (free)

// ---------------- Kernel A: M[b] += K_chunk^T @ Q_chunk (atomic) -------------
__global__ __launch_bounds__(256) void ktq_kernel(const float* __restrict__ K,
                                                  const float* __restrict__ Q,
                                                  float* __restrict__ M) {
    __shared__ float Ks[SCHUNK * DIM];   // 32 KB
    __shared__ float Qs[SCHUNK * DIM];   // 32 KB
    const int b     = blockIdx.y;
    const int chunk = blockIdx.x;
    const int t     = threadIdx.x;

    const float* Kb = K + (size_t)b * SEQ * DIM + (size_t)chunk * SCHUNK * DIM;
    const float* Qb = Q + (size_t)b * SEQ * DIM + (size_t)chunk * SCHUNK * DIM;

    // Stage: SCHUNK*DIM = 8192 floats = 2048 float4; 256 threads -> 8 each.
#pragma unroll
    for (int i = 0; i < 8; ++i) {
        int idx = i * 256 + t;
        ((float4*)Ks)[idx] = ((const float4*)Kb)[idx];
        ((float4*)Qs)[idx] = ((const float4*)Qb)[idx];
    }
    __syncthreads();

    const int tx = t & 15;   // -> d  (Q) columns  tx*4 .. tx*4+3
    const int ty = t >> 4;   // -> d' (K) rows     ty*4 .. ty*4+3
    float acc[4][4];
#pragma unroll
    for (int i = 0; i < 4; ++i)
#pragma unroll
        for (int j = 0; j < 4; ++j) acc[i][j] = 0.f;

    for (int s = 0; s < SCHUNK; ++s) {
        float4 ak = *(const float4*)&Ks[s * DIM + ty * 4];  // broadcast across tx
        float4 bq = *(const float4*)&Qs[s * DIM + tx * 4];  // contiguous across tx
        float av[4] = {ak.x, ak.y, ak.z, ak.w};
        float bv[4] = {bq.x, bq.y, bq.z, bq.w};
#pragma unroll
        for (int i = 0; i < 4; ++i)
#pragma unroll
            for (int j = 0; j < 4; ++j) acc[i][j] += av[i] * bv[j];
    }

    float* Mb = M + b * DIM * DIM;
#pragma unroll
    for (int i = 0; i < 4; ++i)
#pragma unroll
        for (int j = 0; j < 4; ++j)
            atomicAdd(&Mb[(ty * 4 + i) * DIM + tx * 4 + j], acc[i][j]);
}

// ---------------- Kernel B: out_rows = V_rows @ M[b] -------------------------
__global__ __launch_bounds__(256) void vm_kernel(const float* __restrict__ V,
                                                 const float* __restrict__ M,
                                                 float* __restrict__ O) {
    __shared__ float Ml[DIM * DIM];      // 16 KB, M[d'][d]
    __shared__ float Vs[RBLK * VPAD];    // 17 KB, padded rows
    const int b  = blockIdx.y;
    const int rb = blockIdx.x;
    const int t  = threadIdx.x;

    const float* Mb = M + b * DIM * DIM;
    const float* Vb = V + (size_t)b * SEQ * DIM + (size_t)rb * RBLK * DIM;

    // Stage M: 4096 floats = 1024 float4; 4 per thread.
#pragma unroll
    for (int i = 0; i < 4; ++i) {
        int idx = i * 256 + t;
        ((float4*)Ml)[idx] = ((const float4*)Mb)[idx];
    }
    // Stage V rows (RBLK*DIM = 4096 floats = 1024 float4) into padded layout.
    // Row stride 68 floats = 272 B = 17*16 B -> every float4 slot stays 16B-aligned.
#pragma unroll
    for (int i = 0; i < 4; ++i) {
        int idx = i * 256 + t;        // float4 index in [64][16] logical layout
        int row = idx >> 4;
        int col = (idx & 15) * 4;
        float4 v = ((const float4*)Vb)[idx];
        *(float4*)&Vs[row * VPAD + col] = v;
    }
    __syncthreads();

    const int tx = t & 15;   // output cols  d  = tx*4 .. +3
    const int ty = t >> 4;   // output rows  v  = ty*4 .. +3 (of this 64-row block)
    float acc[4][4];
#pragma unroll
    for (int i = 0; i < 4; ++i)
#pragma unroll
        for (int j = 0; j < 4; ++j) acc[i][j] = 0.f;

    for (int dp = 0; dp < DIM; ++dp) {
        float4 mv = *(const float4*)&Ml[dp * DIM + tx * 4];  // contiguous across tx
        float m[4] = {mv.x, mv.y, mv.z, mv.w};
        float a[4];
#pragma unroll
        for (int i = 0; i < 4; ++i) a[i] = Vs[(ty * 4 + i) * VPAD + dp];
#pragma unroll
        for (int i = 0; i < 4; ++i)
#pragma unroll
            for (int j = 0; j < 4; ++j) acc[i][j] += a[i] * m[j];
    }

    float* Ob = O + (size_t)b * SEQ * DIM + (size_t)rb * RBLK * DIM;
#pragma unroll
    for (int i = 0; i < 4; ++i) {
        float4 o = {acc[i][0], acc[i][1], acc[i][2], acc[i][3]};
        *(float4*)&Ob[(ty * 4 + i) * DIM + tx * 4] = o;
    }
}

extern "C" void kernel_launch(void* const* d_in, const int* in_sizes, int n_in,
                              void* d_out, int out_size, void* d_ws, size_t ws_size,
                              hipStream_t stream) {
    const float* Q = (const float*)d_in[0];
    const float* K = (const float*)d_in[1];
    const float* V = (const float*)d_in[2];
    float* O = (float*)d_out;
    float* M = (float*)d_ws;   // BATCH * 64 * 64 floats = 256 KB

    // Workspace is poisoned to 0xAA before every call -> zero the M region.
    hipMemsetAsync(M, 0, (size_t)BATCH * DIM * DIM * sizeof(float), stream);

    dim3 gridA(NCHUNK, BATCH);       // 16 x 16 = 256 blocks
    ktq_kernel<<<gridA, 256, 0, stream>>>(K, Q, M);

    dim3 gridB(SEQ / RBLK, BATCH);   // 32 x 16 = 512 blocks
    vm_kernel<<<gridB, 256, 0, stream>>>(V, M, O);
}